// Round 1
// baseline (1575.977 us; speedup 1.0000x reference)
//
#include <hip/hip_runtime.h>

typedef __bf16 bf16_t;
typedef bf16_t bf16x8 __attribute__((ext_vector_type(8)));
typedef bf16_t bf16x4 __attribute__((ext_vector_type(4)));
typedef float f32x4 __attribute__((ext_vector_type(4)));

#define M_ROWS 16400
#define M_PAD 16512   // 129 * 128
#define S_LEN 1025

// ---------------- fp32 -> bf16 convert (weights) ----------------
__global__ __launch_bounds__(256) void cvt_kernel(const float* __restrict__ in,
                                                  bf16_t* __restrict__ out, int n4) {
  int i = blockIdx.x * 256 + threadIdx.x;
  if (i < n4) {
    float4 v = ((const float4*)in)[i];
    bf16x4 o;
    o[0] = (bf16_t)v.x; o[1] = (bf16_t)v.y; o[2] = (bf16_t)v.z; o[3] = (bf16_t)v.w;
    ((bf16x4*)out)[i] = o;
  }
}

// ---------------- LayerNorm (fp32 in -> bf16 out) ----------------
__global__ __launch_bounds__(256) void ln_kernel(const float* __restrict__ x,
                                                 const float* __restrict__ g,
                                                 const float* __restrict__ bta,
                                                 bf16_t* __restrict__ o) {
  const long row = blockIdx.x;
  const int t = threadIdx.x;
  const float4 v = ((const float4*)(x + row * 1024))[t];
  float s = v.x + v.y + v.z + v.w;
  float sq = v.x * v.x + v.y * v.y + v.z * v.z + v.w * v.w;
#pragma unroll
  for (int off = 32; off > 0; off >>= 1) {
    s += __shfl_down(s, off);
    sq += __shfl_down(sq, off);
  }
  __shared__ float red[16];
  const int w = t >> 6, lane = t & 63;
  if (lane == 0) { red[w] = s; red[8 + w] = sq; }
  __syncthreads();
  if (t == 0) {
    const float ts = red[0] + red[1] + red[2] + red[3];
    const float tq = red[8] + red[9] + red[10] + red[11];
    const float mean = ts * (1.0f / 1024.0f);
    const float var = tq * (1.0f / 1024.0f) - mean * mean;
    red[0] = mean;
    red[1] = rsqrtf(var + 1e-5f);
  }
  __syncthreads();
  const float mean = red[0], rstd = red[1];
  const float4 gg = ((const float4*)g)[t];
  const float4 bb = ((const float4*)bta)[t];
  bf16x4 ov;
  ov[0] = (bf16_t)((v.x - mean) * rstd * gg.x + bb.x);
  ov[1] = (bf16_t)((v.y - mean) * rstd * gg.y + bb.y);
  ov[2] = (bf16_t)((v.z - mean) * rstd * gg.z + bb.z);
  ov[3] = (bf16_t)((v.w - mean) * rstd * gg.w + bb.w);
  ((bf16x4*)(o + row * 1024))[t] = ov;
}

// ---------------- GEMM C = A @ W^T (+epilogue), m97 structure ----------------
// A [Mpad,K] bf16 row-major, W [N,K] bf16 row-major. 128x128 tile, BK=32,
// 256 thr = 4 waves in 2x2, each wave 4x4 MFMA 16x16x32 tiles.
enum { EPI_QKV = 0, EPI_PROJ = 1, EPI_FC1 = 2, EPI_FC2 = 3 };

template <int EPI>
__global__ __launch_bounds__(256) void gemm_bt(const bf16_t* __restrict__ A,
                                               const bf16_t* __restrict__ W,
                                               const float* __restrict__ bias,
                                               const float* __restrict__ resid,
                                               const float* __restrict__ ls,
                                               bf16_t* __restrict__ outb,
                                               float* __restrict__ outf,
                                               int M, int N, int K) {
  __shared__ bf16_t ldsA[128 * 32];
  __shared__ bf16_t ldsB[128 * 32];
  const int t = threadIdx.x;
  const int m0 = blockIdx.x * 128;
  const int n0 = blockIdx.y * 128;
  const int w = t >> 6;
  const int lane = t & 63;
  const int wm = (w >> 1) * 64;
  const int wn = (w & 1) * 64;
  const int ln = lane & 15;
  const int quad = lane >> 4;

  const f32x4 zero4 = {0.0f, 0.0f, 0.0f, 0.0f};
  f32x4 acc[4][4];
#pragma unroll
  for (int i = 0; i < 4; ++i)
#pragma unroll
    for (int j = 0; j < 4; ++j) acc[i][j] = zero4;

  // staging: chunk c (of 512) covers row=c>>2 (64B rows), 16B sub-chunk c&3
  const int r0 = t >> 2, kc0 = (t & 3) * 8;
  const int r1 = (t + 256) >> 2, kc1 = ((t + 256) & 3) * 8;
  const bf16_t* a0 = A + (long)(m0 + r0) * K + kc0;
  const bf16_t* a1 = A + (long)(m0 + r1) * K + kc1;
  const bf16_t* b0 = W + (long)(n0 + r0) * K + kc0;
  const bf16_t* b1 = W + (long)(n0 + r1) * K + kc1;

  for (int kt = 0; kt < K; kt += 32) {
    __syncthreads();
    __builtin_amdgcn_global_load_lds((const __attribute__((address_space(1))) void*)(a0 + kt),
                                     (__attribute__((address_space(3))) void*)&ldsA[t * 8], 16, 0, 0);
    __builtin_amdgcn_global_load_lds((const __attribute__((address_space(1))) void*)(a1 + kt),
                                     (__attribute__((address_space(3))) void*)&ldsA[(t + 256) * 8], 16, 0, 0);
    __builtin_amdgcn_global_load_lds((const __attribute__((address_space(1))) void*)(b0 + kt),
                                     (__attribute__((address_space(3))) void*)&ldsB[t * 8], 16, 0, 0);
    __builtin_amdgcn_global_load_lds((const __attribute__((address_space(1))) void*)(b1 + kt),
                                     (__attribute__((address_space(3))) void*)&ldsB[(t + 256) * 8], 16, 0, 0);
    __syncthreads();

    bf16x8 af[4], bfr[4];
#pragma unroll
    for (int mt = 0; mt < 4; ++mt)
      af[mt] = *(const bf16x8*)&ldsA[(wm + mt * 16 + ln) * 32 + quad * 8];
#pragma unroll
    for (int nt = 0; nt < 4; ++nt)
      bfr[nt] = *(const bf16x8*)&ldsB[(wn + nt * 16 + ln) * 32 + quad * 8];
#pragma unroll
    for (int mt = 0; mt < 4; ++mt)
#pragma unroll
      for (int nt = 0; nt < 4; ++nt)
        acc[mt][nt] = __builtin_amdgcn_mfma_f32_16x16x32_bf16(af[mt], bfr[nt], acc[mt][nt], 0, 0, 0);
  }

  // epilogue: C/D layout col=lane&15, row=quad*4+reg (m89-verified)
#pragma unroll
  for (int nt = 0; nt < 4; ++nt) {
    const int n = n0 + wn + nt * 16 + ln;
    const float bn = bias[n];
    float lsn = 0.0f;
    if (EPI == EPI_PROJ || EPI == EPI_FC2) lsn = ls[n];
#pragma unroll
    for (int mt = 0; mt < 4; ++mt) {
#pragma unroll
      for (int r = 0; r < 4; ++r) {
        const int m = m0 + wm + mt * 16 + quad * 4 + r;
        if (m < M) {
          const float c = acc[mt][nt][r] + bn;
          const long idx = (long)m * N + n;
          if (EPI == EPI_QKV) {
            outb[idx] = (bf16_t)c;
          } else if (EPI == EPI_FC1) {
            const float gl = 0.5f * c * (1.0f + erff(c * 0.70710678118654752f));
            outb[idx] = (bf16_t)gl;
          } else {
            outf[idx] = resid[idx] + lsn * c;  // PROJ: hidden+ls1*c ; FC2: d_out+ls2*c
          }
        }
      }
    }
  }
}

// ---------------- Flash attention ----------------
// grid (17 qtiles, 256 bh). 4 waves/block, each wave owns 16 Q rows.
// K tile 32 keys staged in LDS; V staged transposed; P via LDS round-trip.
__global__ __launch_bounds__(256) void attn_kernel(const bf16_t* __restrict__ qkv,
                                                   bf16_t* __restrict__ out) {
  const int bh = blockIdx.y;
  const int b = bh >> 4, h = bh & 15;
  const int q0 = blockIdx.x * 64;
  const int t = threadIdx.x;
  const int wv = t >> 6, lane = t & 63;
  const int ln = lane & 15, quad = lane >> 4;

  __shared__ bf16_t ldsK[32][72];      // [key][dim], +8 pad
  __shared__ bf16_t ldsVt[64][40];     // [dim][key], +8 pad
  __shared__ bf16_t ldsP[4][16][40];   // per-wave [query][key], +8 pad

  const long rowbase = (long)b * S_LEN;

  int qrow = q0 + wv * 16 + ln;
  if (qrow > S_LEN - 1) qrow = S_LEN - 1;
  const bf16_t* qp = qkv + (rowbase + qrow) * 3072 + h * 64;
  const bf16x8 qf0 = *(const bf16x8*)(qp + quad * 8);        // dims 0..31
  const bf16x8 qf1 = *(const bf16x8*)(qp + 32 + quad * 8);   // dims 32..63

  const f32x4 zero4 = {0.0f, 0.0f, 0.0f, 0.0f};
  f32x4 oacc[4];
  float m_run[4], l_run[4];
#pragma unroll
  for (int i = 0; i < 4; ++i) { oacc[i] = zero4; m_run[i] = -1e30f; l_run[i] = 0.0f; }

  const int sr = t >> 3;        // staging key row 0..31
  const int sc = (t & 7) * 8;   // staging dim chunk

  for (int k0 = 0; k0 < S_LEN; k0 += 32) {
    __syncthreads();
    {
      int krow = k0 + sr;
      if (krow > S_LEN - 1) krow = S_LEN - 1;
      const bf16_t* kp = qkv + (rowbase + krow) * 3072 + 1024 + h * 64 + sc;
      *(bf16x8*)&ldsK[sr][sc] = *(const bf16x8*)kp;
      const bf16x8 vvv = *(const bf16x8*)(kp + 1024);
#pragma unroll
      for (int j = 0; j < 8; ++j) ldsVt[sc + j][sr] = vvv[j];
    }
    __syncthreads();

    // scores: D[q][key] ; B[k=dim][n=key] read from ldsK rows (contiguous)
    f32x4 s[2];
#pragma unroll
    for (int nt = 0; nt < 2; ++nt) {
      const bf16x8 kf0 = *(const bf16x8*)&ldsK[nt * 16 + ln][quad * 8];
      const bf16x8 kf1 = *(const bf16x8*)&ldsK[nt * 16 + ln][32 + quad * 8];
      f32x4 a = zero4;
      a = __builtin_amdgcn_mfma_f32_16x16x32_bf16(qf0, kf0, a, 0, 0, 0);
      a = __builtin_amdgcn_mfma_f32_16x16x32_bf16(qf1, kf1, a, 0, 0, 0);
      const int key = k0 + nt * 16 + ln;
      const bool valid = (key < S_LEN);
#pragma unroll
      for (int r = 0; r < 4; ++r) s[nt][r] = valid ? a[r] * 0.125f : -1e30f;
    }

    // row max across the 16 lanes of each quad-group
    float mx[4];
#pragma unroll
    for (int r = 0; r < 4; ++r) mx[r] = fmaxf(s[0][r], s[1][r]);
#pragma unroll
    for (int off = 1; off < 16; off <<= 1)
#pragma unroll
      for (int r = 0; r < 4; ++r) mx[r] = fmaxf(mx[r], __shfl_xor(mx[r], off));

    float alpha[4];
#pragma unroll
    for (int r = 0; r < 4; ++r) {
      const float mnew = fmaxf(m_run[r], mx[r]);
      alpha[r] = __expf(m_run[r] - mnew);
      m_run[r] = mnew;
    }

    float rs[4] = {0.0f, 0.0f, 0.0f, 0.0f};
#pragma unroll
    for (int nt = 0; nt < 2; ++nt)
#pragma unroll
      for (int r = 0; r < 4; ++r) {
        const float p = __expf(s[nt][r] - m_run[r]);
        rs[r] += p;
        ldsP[wv][quad * 4 + r][nt * 16 + ln] = (bf16_t)p;
      }
#pragma unroll
    for (int off = 1; off < 16; off <<= 1)
#pragma unroll
      for (int r = 0; r < 4; ++r) rs[r] += __shfl_xor(rs[r], off);
#pragma unroll
    for (int r = 0; r < 4; ++r) l_run[r] = l_run[r] * alpha[r] + rs[r];

#pragma unroll
    for (int dt = 0; dt < 4; ++dt)
#pragma unroll
      for (int r = 0; r < 4; ++r) oacc[dt][r] *= alpha[r];

    // PV: A=P (A[m=q][k=key]), B[k=key][n=dim] from ldsVt rows (contiguous)
    const bf16x8 pf = *(const bf16x8*)&ldsP[wv][ln][quad * 8];
#pragma unroll
    for (int dt = 0; dt < 4; ++dt) {
      const bf16x8 vf = *(const bf16x8*)&ldsVt[dt * 16 + ln][quad * 8];
      oacc[dt] = __builtin_amdgcn_mfma_f32_16x16x32_bf16(pf, vf, oacc[dt], 0, 0, 0);
    }
  }

#pragma unroll
  for (int r = 0; r < 4; ++r) {
    const int q = q0 + wv * 16 + quad * 4 + r;
    if (q < S_LEN) {
      const float inv = 1.0f / l_run[r];
#pragma unroll
      for (int dt = 0; dt < 4; ++dt)
        out[(rowbase + q) * 1024 + h * 64 + dt * 16 + ln] = (bf16_t)(oacc[dt][r] * inv);
    }
  }
}

// ---------------- launch ----------------
extern "C" void kernel_launch(void* const* d_in, const int* in_sizes, int n_in,
                              void* d_out, int out_size, void* d_ws, size_t ws_size,
                              hipStream_t stream) {
  (void)in_sizes; (void)n_in; (void)out_size; (void)ws_size;
  const float* hidden = (const float*)d_in[0];
  const float* n1g = (const float*)d_in[1];
  const float* n1b = (const float*)d_in[2];
  const float* qkv_w = (const float*)d_in[3];
  const float* qkv_b = (const float*)d_in[4];
  const float* proj_w = (const float*)d_in[5];
  const float* proj_b = (const float*)d_in[6];
  const float* ls1 = (const float*)d_in[7];
  const float* n2g = (const float*)d_in[8];
  const float* n2b = (const float*)d_in[9];
  const float* fc1_w = (const float*)d_in[10];
  const float* fc1_b = (const float*)d_in[11];
  const float* fc2_w = (const float*)d_in[12];
  const float* fc2_b = (const float*)d_in[13];
  const float* ls2 = (const float*)d_in[14];
  float* out = (float*)d_out;

  // workspace layout (bytes):
  //  R1: Mpad*1024 bf16 = 33,816,576   (xnorm -> attn_out -> ynorm)
  //  R2: Mpad*4096 bf16 = 135,266,304  (qkv [Mpad*3072] -> gelu [Mpad*4096])
  //  W : bf16 weights 25,165,824       total ~194.3 MB
  char* ws = (char*)d_ws;
  bf16_t* R1 = (bf16_t*)ws;
  bf16_t* R2 = (bf16_t*)(ws + 33816576L);
  bf16_t* wqkv = (bf16_t*)(ws + 33816576L + 135266304L);
  bf16_t* wproj = wqkv + 3145728;
  bf16_t* wfc1 = wproj + 1048576;
  bf16_t* wfc2 = wfc1 + 4194304;

  cvt_kernel<<<3072, 256, 0, stream>>>(qkv_w, wqkv, 786432);
  cvt_kernel<<<1024, 256, 0, stream>>>(proj_w, wproj, 262144);
  cvt_kernel<<<4096, 256, 0, stream>>>(fc1_w, wfc1, 1048576);
  cvt_kernel<<<4096, 256, 0, stream>>>(fc2_w, wfc2, 1048576);

  // LN1: hidden -> R1 (bf16)
  ln_kernel<<<M_ROWS, 256, 0, stream>>>(hidden, n1g, n1b, R1);

  // QKV: R1 @ wqkv^T + b -> R2 bf16 [M,3072]
  gemm_bt<EPI_QKV><<<dim3(129, 24), 256, 0, stream>>>(R1, wqkv, qkv_b, nullptr, nullptr,
                                                      R2, nullptr, M_ROWS, 3072, 1024);

  // attention: R2 -> R1 bf16 [M,1024]
  attn_kernel<<<dim3(17, 256), 256, 0, stream>>>(R2, R1);

  // proj + residual: out = hidden + ls1*(R1 @ wproj^T + b)  (fp32)
  gemm_bt<EPI_PROJ><<<dim3(129, 8), 256, 0, stream>>>(R1, wproj, proj_b, hidden, ls1,
                                                      nullptr, out, M_ROWS, 1024, 1024);

  // LN2: out -> R1 (bf16)
  ln_kernel<<<M_ROWS, 256, 0, stream>>>(out, n2g, n2b, R1);

  // FC1 + GELU: R1 @ wfc1^T + b -> R2 bf16 [M,4096]
  gemm_bt<EPI_FC1><<<dim3(129, 32), 256, 0, stream>>>(R1, wfc1, fc1_b, nullptr, nullptr,
                                                      R2, nullptr, M_ROWS, 4096, 1024);

  // FC2 + residual (in-place): out = out + ls2*(R2 @ wfc2^T + b)
  gemm_bt<EPI_FC2><<<dim3(129, 8), 256, 0, stream>>>(R2, wfc2, fc2_b, out, ls2,
                                                     nullptr, out, M_ROWS, 1024, 4096);
}

// Round 2
// 1384.854 us; speedup vs baseline: 1.1380x; 1.1380x over previous
//
#include <hip/hip_runtime.h>

typedef __bf16 bf16_t;
typedef bf16_t bf16x8 __attribute__((ext_vector_type(8)));
typedef bf16_t bf16x4 __attribute__((ext_vector_type(4)));
typedef float f32x4 __attribute__((ext_vector_type(4)));

#define M_ROWS 16400
#define S_LEN 1025
#define SP 1152   // padded seq stride for V^T (9*128)

// ---------------- fp32 -> bf16 convert (weights) ----------------
__global__ __launch_bounds__(256) void cvt_kernel(const float* __restrict__ in,
                                                  bf16_t* __restrict__ out, int n4) {
  int i = blockIdx.x * 256 + threadIdx.x;
  if (i < n4) {
    float4 v = ((const float4*)in)[i];
    bf16x4 o;
    o[0] = (bf16_t)v.x; o[1] = (bf16_t)v.y; o[2] = (bf16_t)v.z; o[3] = (bf16_t)v.w;
    ((bf16x4*)out)[i] = o;
  }
}

// ---------------- LayerNorm (fp32 in -> bf16 out) ----------------
__global__ __launch_bounds__(256) void ln_kernel(const float* __restrict__ x,
                                                 const float* __restrict__ g,
                                                 const float* __restrict__ bta,
                                                 bf16_t* __restrict__ o) {
  const long row = blockIdx.x;
  const int t = threadIdx.x;
  const float4 v = ((const float4*)(x + row * 1024))[t];
  float s = v.x + v.y + v.z + v.w;
  float sq = v.x * v.x + v.y * v.y + v.z * v.z + v.w * v.w;
#pragma unroll
  for (int off = 32; off > 0; off >>= 1) {
    s += __shfl_down(s, off);
    sq += __shfl_down(sq, off);
  }
  __shared__ float red[16];
  const int w = t >> 6, lane = t & 63;
  if (lane == 0) { red[w] = s; red[8 + w] = sq; }
  __syncthreads();
  if (t == 0) {
    const float ts = red[0] + red[1] + red[2] + red[3];
    const float tq = red[8] + red[9] + red[10] + red[11];
    const float mean = ts * (1.0f / 1024.0f);
    const float var = tq * (1.0f / 1024.0f) - mean * mean;
    red[0] = mean;
    red[1] = rsqrtf(var + 1e-5f);
  }
  __syncthreads();
  const float mean = red[0], rstd = red[1];
  const float4 gg = ((const float4*)g)[t];
  const float4 bb = ((const float4*)bta)[t];
  bf16x4 ov;
  ov[0] = (bf16_t)((v.x - mean) * rstd * gg.x + bb.x);
  ov[1] = (bf16_t)((v.y - mean) * rstd * gg.y + bb.y);
  ov[2] = (bf16_t)((v.z - mean) * rstd * gg.z + bb.z);
  ov[3] = (bf16_t)((v.w - mean) * rstd * gg.w + bb.w);
  ((bf16x4*)(o + row * 1024))[t] = ov;
}

// ---------------- GEMM C = A @ W^T (+epilogue), m97 structure ----------------
// A [*,K] bf16 row-major, W [N,K] bf16 row-major. 128x128 tile, BK=32,
// 256 thr = 4 waves in 2x2, each wave 4x4 MFMA 16x16x32 tiles.
// Grid: x = n-tile (fast), y = m-tile -> A streamed once per n-generation.
enum { EPI_QKV = 0, EPI_PROJ = 1, EPI_FC1 = 2, EPI_FC2 = 3 };

template <int EPI>
__global__ __launch_bounds__(256) void gemm_bt(const bf16_t* __restrict__ A,
                                               const bf16_t* __restrict__ W,
                                               const float* __restrict__ bias,
                                               const float* __restrict__ resid,
                                               const float* __restrict__ ls,
                                               bf16_t* __restrict__ outb,
                                               float* __restrict__ outf,
                                               bf16_t* __restrict__ vt,
                                               int M, int N, int K) {
  __shared__ bf16_t ldsA[128 * 32];
  __shared__ bf16_t ldsB[128 * 32];
  const int t = threadIdx.x;
  const int n0 = blockIdx.x * 128;
  const int m0 = blockIdx.y * 128;
  const int w = t >> 6;
  const int lane = t & 63;
  const int wm = (w >> 1) * 64;
  const int wn = (w & 1) * 64;
  const int ln = lane & 15;
  const int quad = lane >> 4;

  const f32x4 zero4 = {0.0f, 0.0f, 0.0f, 0.0f};
  f32x4 acc[4][4];
#pragma unroll
  for (int i = 0; i < 4; ++i)
#pragma unroll
    for (int j = 0; j < 4; ++j) acc[i][j] = zero4;

  const int r0 = t >> 2, kc0 = (t & 3) * 8;
  const int r1 = (t + 256) >> 2, kc1 = ((t + 256) & 3) * 8;
  const bf16_t* a0 = A + (long)(m0 + r0) * K + kc0;
  const bf16_t* a1 = A + (long)(m0 + r1) * K + kc1;
  const bf16_t* b0 = W + (long)(n0 + r0) * K + kc0;
  const bf16_t* b1 = W + (long)(n0 + r1) * K + kc1;

  for (int kt = 0; kt < K; kt += 32) {
    __syncthreads();
    __builtin_amdgcn_global_load_lds((const __attribute__((address_space(1))) void*)(a0 + kt),
                                     (__attribute__((address_space(3))) void*)&ldsA[t * 8], 16, 0, 0);
    __builtin_amdgcn_global_load_lds((const __attribute__((address_space(1))) void*)(a1 + kt),
                                     (__attribute__((address_space(3))) void*)&ldsA[(t + 256) * 8], 16, 0, 0);
    __builtin_amdgcn_global_load_lds((const __attribute__((address_space(1))) void*)(b0 + kt),
                                     (__attribute__((address_space(3))) void*)&ldsB[t * 8], 16, 0, 0);
    __builtin_amdgcn_global_load_lds((const __attribute__((address_space(1))) void*)(b1 + kt),
                                     (__attribute__((address_space(3))) void*)&ldsB[(t + 256) * 8], 16, 0, 0);
    __syncthreads();

    bf16x8 af[4], bfr[4];
#pragma unroll
    for (int mt = 0; mt < 4; ++mt)
      af[mt] = *(const bf16x8*)&ldsA[(wm + mt * 16 + ln) * 32 + quad * 8];
#pragma unroll
    for (int nt = 0; nt < 4; ++nt)
      bfr[nt] = *(const bf16x8*)&ldsB[(wn + nt * 16 + ln) * 32 + quad * 8];
#pragma unroll
    for (int mt = 0; mt < 4; ++mt)
#pragma unroll
      for (int nt = 0; nt < 4; ++nt)
        acc[mt][nt] = __builtin_amdgcn_mfma_f32_16x16x32_bf16(af[mt], bfr[nt], acc[mt][nt], 0, 0, 0);
  }

  // epilogue: C/D layout col=lane&15, row=quad*4+reg (m89-verified)
  if (EPI == EPI_QKV && n0 >= 2048) {
    // V part -> transposed store vt[bh][dim][s], consecutive regs = consecutive s
#pragma unroll
    for (int nt = 0; nt < 4; ++nt) {
      const int n = n0 + wn + nt * 16 + ln;
      const float bn = bias[n];
      const int h = (n >> 6) - 32;
      const int dim = n & 63;
      const long vrow = ((long)h * 64 + dim) * SP;  // + b*64*64*SP added per element
#pragma unroll
      for (int mt = 0; mt < 4; ++mt) {
#pragma unroll
        for (int r = 0; r < 4; ++r) {
          const int m = m0 + wm + mt * 16 + quad * 4 + r;
          if (m < M) {
            const int b = (unsigned)m / 1025u;
            const int s = m - b * 1025;
            vt[((long)b * 16 * 64) * SP + vrow + s] = (bf16_t)(acc[mt][nt][r] + bn);
          }
        }
      }
    }
    return;
  }
#pragma unroll
  for (int nt = 0; nt < 4; ++nt) {
    const int n = n0 + wn + nt * 16 + ln;
    const float bn = bias[n];
    float lsn = 0.0f;
    if (EPI == EPI_PROJ || EPI == EPI_FC2) lsn = ls[n];
#pragma unroll
    for (int mt = 0; mt < 4; ++mt) {
#pragma unroll
      for (int r = 0; r < 4; ++r) {
        const int m = m0 + wm + mt * 16 + quad * 4 + r;
        if (m < M) {
          const float c = acc[mt][nt][r] + bn;
          if (EPI == EPI_QKV) {
            outb[(long)m * 2048 + n] = (bf16_t)c;   // Q/K at stride 2048
          } else if (EPI == EPI_FC1) {
            const float gl = 0.5f * c * (1.0f + erff(c * 0.70710678118654752f));
            outb[(long)m * N + n] = (bf16_t)gl;
          } else {
            outf[(long)m * N + n] = resid[(long)m * N + n] + lsn * c;
          }
        }
      }
    }
  }
}

// ---------------- Flash attention, 128-key tiles ----------------
// grid (17 qtiles, 256 bh). 4 waves/block, each wave owns 16 Q rows.
// K staged [128][72] (b128 writes), V^T staged [64][136] from global vt.
__global__ __launch_bounds__(256) void attn_kernel(const bf16_t* __restrict__ qk,
                                                   const bf16_t* __restrict__ vt,
                                                   bf16_t* __restrict__ out) {
  const int bh = blockIdx.y;
  const int b = bh >> 4, h = bh & 15;
  const int q0 = blockIdx.x * 64;
  const int t = threadIdx.x;
  const int wv = t >> 6, lane = t & 63;
  const int ln = lane & 15, quad = lane >> 4;

  __shared__ bf16_t ldsK[128][72];       // [key][dim], stride 72 (conflict-free frags)
  __shared__ bf16_t ldsV[64][136];       // [dim][key], stride 136
  __shared__ bf16_t ldsP[4][16][136];    // per-wave [q][key]

  const long rowbase = (long)b * S_LEN;

  int qrow = q0 + wv * 16 + ln;
  if (qrow > S_LEN - 1) qrow = S_LEN - 1;
  const bf16_t* qp = qk + (rowbase + qrow) * 2048 + h * 64;
  const bf16x8 qf0 = *(const bf16x8*)(qp + quad * 8);
  const bf16x8 qf1 = *(const bf16x8*)(qp + 32 + quad * 8);

  const bf16_t* vbase = vt + (long)bh * 64 * SP;

  const f32x4 zero4 = {0.0f, 0.0f, 0.0f, 0.0f};
  f32x4 oacc[4];
  float m_run[4], l_run[4];
#pragma unroll
  for (int i = 0; i < 4; ++i) { oacc[i] = zero4; m_run[i] = -1e30f; l_run[i] = 0.0f; }

  for (int k0 = 0; k0 < S_LEN; k0 += 128) {
    __syncthreads();
    // stage K: 128 rows x 64 dims = 1024 16B-chunks, 4 per thread
#pragma unroll
    for (int i = 0; i < 4; ++i) {
      const int slot = t + i * 256;
      const int key = slot >> 3, ch = (slot & 7) * 8;
      int krow = k0 + key;
      if (krow > S_LEN - 1) krow = S_LEN - 1;
      *(bf16x8*)&ldsK[key][ch] =
          *(const bf16x8*)(qk + (rowbase + krow) * 2048 + 1024 + h * 64 + ch);
    }
    // stage V^T: 64 dims x 128 keys = 1024 16B-chunks
#pragma unroll
    for (int i = 0; i < 4; ++i) {
      const int slot = t + i * 256;
      const int dim = slot >> 4, kc = (slot & 15) * 8;
      *(bf16x8*)&ldsV[dim][kc] = *(const bf16x8*)(vbase + (long)dim * SP + k0 + kc);
    }
    __syncthreads();

    // scores S[q][key] for 8 key-subtiles
    f32x4 s[8];
#pragma unroll
    for (int nt = 0; nt < 8; ++nt) {
      const bf16x8 kf0 = *(const bf16x8*)&ldsK[nt * 16 + ln][quad * 8];
      const bf16x8 kf1 = *(const bf16x8*)&ldsK[nt * 16 + ln][32 + quad * 8];
      f32x4 a = zero4;
      a = __builtin_amdgcn_mfma_f32_16x16x32_bf16(qf0, kf0, a, 0, 0, 0);
      a = __builtin_amdgcn_mfma_f32_16x16x32_bf16(qf1, kf1, a, 0, 0, 0);
      const bool valid = (k0 + nt * 16 + ln) < S_LEN;
#pragma unroll
      for (int r = 0; r < 4; ++r) s[nt][r] = valid ? a[r] * 0.125f : -1e30f;
    }

    // online softmax (one pass per 128 keys)
    float mx[4];
#pragma unroll
    for (int r = 0; r < 4; ++r) mx[r] = s[0][r];
#pragma unroll
    for (int nt = 1; nt < 8; ++nt)
#pragma unroll
      for (int r = 0; r < 4; ++r) mx[r] = fmaxf(mx[r], s[nt][r]);
#pragma unroll
    for (int off = 1; off < 16; off <<= 1)
#pragma unroll
      for (int r = 0; r < 4; ++r) mx[r] = fmaxf(mx[r], __shfl_xor(mx[r], off));

    float alpha[4];
#pragma unroll
    for (int r = 0; r < 4; ++r) {
      const float mnew = fmaxf(m_run[r], mx[r]);
      alpha[r] = __expf(m_run[r] - mnew);
      m_run[r] = mnew;
    }

    float rs[4] = {0.0f, 0.0f, 0.0f, 0.0f};
#pragma unroll
    for (int nt = 0; nt < 8; ++nt)
#pragma unroll
      for (int r = 0; r < 4; ++r) {
        const float p = __expf(s[nt][r] - m_run[r]);
        rs[r] += p;
        ldsP[wv][quad * 4 + r][nt * 16 + ln] = (bf16_t)p;
      }
#pragma unroll
    for (int off = 1; off < 16; off <<= 1)
#pragma unroll
      for (int r = 0; r < 4; ++r) rs[r] += __shfl_xor(rs[r], off);
#pragma unroll
    for (int r = 0; r < 4; ++r) l_run[r] = l_run[r] * alpha[r] + rs[r];

#pragma unroll
    for (int dt = 0; dt < 4; ++dt)
#pragma unroll
      for (int r = 0; r < 4; ++r) oacc[dt][r] *= alpha[r];

    // PV: A=P[q][key] (per-wave LDS), B=V^T[dim][key] rows
#pragma unroll
    for (int ko = 0; ko < 4; ++ko) {
      const bf16x8 pf = *(const bf16x8*)&ldsP[wv][ln][ko * 32 + quad * 8];
#pragma unroll
      for (int dt = 0; dt < 4; ++dt) {
        const bf16x8 vf = *(const bf16x8*)&ldsV[dt * 16 + ln][ko * 32 + quad * 8];
        oacc[dt] = __builtin_amdgcn_mfma_f32_16x16x32_bf16(pf, vf, oacc[dt], 0, 0, 0);
      }
    }
  }

#pragma unroll
  for (int r = 0; r < 4; ++r) {
    const int q = q0 + wv * 16 + quad * 4 + r;
    if (q < S_LEN) {
      const float inv = 1.0f / l_run[r];
#pragma unroll
      for (int dt = 0; dt < 4; ++dt)
        out[(rowbase + q) * 1024 + h * 64 + dt * 16 + ln] = (bf16_t)(oacc[dt][r] * inv);
    }
  }
}

// ---------------- launch ----------------
extern "C" void kernel_launch(void* const* d_in, const int* in_sizes, int n_in,
                              void* d_out, int out_size, void* d_ws, size_t ws_size,
                              hipStream_t stream) {
  (void)in_sizes; (void)n_in; (void)out_size; (void)ws_size;
  const float* hidden = (const float*)d_in[0];
  const float* n1g = (const float*)d_in[1];
  const float* n1b = (const float*)d_in[2];
  const float* qkv_w = (const float*)d_in[3];
  const float* qkv_b = (const float*)d_in[4];
  const float* proj_w = (const float*)d_in[5];
  const float* proj_b = (const float*)d_in[6];
  const float* ls1 = (const float*)d_in[7];
  const float* n2g = (const float*)d_in[8];
  const float* n2b = (const float*)d_in[9];
  const float* fc1_w = (const float*)d_in[10];
  const float* fc1_b = (const float*)d_in[11];
  const float* fc2_w = (const float*)d_in[12];
  const float* fc2_b = (const float*)d_in[13];
  const float* ls2 = (const float*)d_in[14];
  float* out = (float*)d_out;

  // workspace layout (bytes):
  //  R1:     16512*1024*2 = 33,816,576   (xnorm -> attn_out -> ynorm)
  //  SHARED: 135,266,304  holds EITHER {qk 67.2MB + vt 37.7MB} (dead after attn)
  //                       OR gelu 16512*4096*2 (written by FC1 after attn)
  //  W:      bf16 weights 25,165,824     total ~194.3 MB (same as round 1)
  char* ws = (char*)d_ws;
  bf16_t* R1 = (bf16_t*)ws;
  char* shared = ws + 33816576L;
  bf16_t* qkbuf = (bf16_t*)shared;                      // [16400, 2048]
  bf16_t* vtbuf = (bf16_t*)(shared + 67174400L);        // [256, 64, SP]
  bf16_t* gelu = (bf16_t*)shared;                       // [16512, 4096]
  bf16_t* wqkv = (bf16_t*)(ws + 33816576L + 135266304L);
  bf16_t* wproj = wqkv + 3145728;
  bf16_t* wfc1 = wproj + 1048576;
  bf16_t* wfc2 = wfc1 + 4194304;

  cvt_kernel<<<3072, 256, 0, stream>>>(qkv_w, wqkv, 786432);
  cvt_kernel<<<1024, 256, 0, stream>>>(proj_w, wproj, 262144);
  cvt_kernel<<<4096, 256, 0, stream>>>(fc1_w, wfc1, 1048576);
  cvt_kernel<<<4096, 256, 0, stream>>>(fc2_w, wfc2, 1048576);

  // LN1: hidden -> R1 (bf16)
  ln_kernel<<<M_ROWS, 256, 0, stream>>>(hidden, n1g, n1b, R1);

  // QKV: R1 @ wqkv^T + b -> Q,K at qkbuf [M,2048], V transposed -> vtbuf
  gemm_bt<EPI_QKV><<<dim3(24, 129), 256, 0, stream>>>(R1, wqkv, qkv_b, nullptr, nullptr,
                                                      qkbuf, nullptr, vtbuf, M_ROWS, 3072, 1024);

  // attention: qkbuf/vtbuf -> R1 bf16 [M,1024]
  attn_kernel<<<dim3(17, 256), 256, 0, stream>>>(qkbuf, vtbuf, R1);

  // proj + residual: out = hidden + ls1*(R1 @ wproj^T + b)  (fp32)
  gemm_bt<EPI_PROJ><<<dim3(8, 129), 256, 0, stream>>>(R1, wproj, proj_b, hidden, ls1,
                                                      nullptr, out, nullptr, M_ROWS, 1024, 1024);

  // LN2: out -> R1 (bf16)
  ln_kernel<<<M_ROWS, 256, 0, stream>>>(out, n2g, n2b, R1);

  // FC1 + GELU: R1 @ wfc1^T + b -> gelu bf16 [M,4096]
  gemm_bt<EPI_FC1><<<dim3(32, 129), 256, 0, stream>>>(R1, wfc1, fc1_b, nullptr, nullptr,
                                                      gelu, nullptr, nullptr, M_ROWS, 4096, 1024);

  // FC2 + residual (in-place): out = out + ls2*(gelu @ wfc2^T + b)
  gemm_bt<EPI_FC2><<<dim3(8, 129), 256, 0, stream>>>(gelu, wfc2, fc2_b, out, ls2,
                                                     nullptr, out, nullptr, M_ROWS, 1024, 4096);
}

// Round 3
// 1240.835 us; speedup vs baseline: 1.2701x; 1.1161x over previous
//
#include <hip/hip_runtime.h>

typedef __bf16 bf16_t;
typedef bf16_t bf16x8 __attribute__((ext_vector_type(8)));
typedef bf16_t bf16x4 __attribute__((ext_vector_type(4)));
typedef float f32x4 __attribute__((ext_vector_type(4)));

#define S_LEN 1025
#define B_ROWS 1032    // per-batch padded rows (8*129); 16*1032 = 16512 = 129 tiles
#define M_P 16512
#define SP 1152        // padded seq stride for V^T (9*128)

// ---------------- fp32 -> bf16 convert (all 4 weight blobs, one launch) ----------------
__global__ __launch_bounds__(256) void cvt_kernel(const float* __restrict__ qkv_w,
                                                  const float* __restrict__ proj_w,
                                                  const float* __restrict__ fc1_w,
                                                  const float* __restrict__ fc2_w,
                                                  bf16_t* __restrict__ out) {
  const int i = blockIdx.x * 256 + threadIdx.x;  // vec4 index, total 3145728
  const float* src;
  int j = i;
  if (j < 786432) src = qkv_w;
  else if ((j -= 786432) < 262144) src = proj_w;
  else if ((j -= 262144) < 1048576) src = fc1_w;
  else { j -= 1048576; src = fc2_w; }
  const float4 v = ((const float4*)src)[j];
  bf16x4 o;
  o[0] = (bf16_t)v.x; o[1] = (bf16_t)v.y; o[2] = (bf16_t)v.z; o[3] = (bf16_t)v.w;
  ((bf16x4*)out)[i] = o;
}

// ---------------- LayerNorm (fp32 unpadded in -> bf16 padded out) ----------------
__global__ __launch_bounds__(256) void ln_kernel(const float* __restrict__ x,
                                                 const float* __restrict__ g,
                                                 const float* __restrict__ bta,
                                                 bf16_t* __restrict__ o) {
  const int s = blockIdx.x, bb = blockIdx.y;
  const int t = threadIdx.x;
  const float4 v = ((const float4*)(x + ((long)bb * S_LEN + s) * 1024))[t];
  float sm = v.x + v.y + v.z + v.w;
  float sq = v.x * v.x + v.y * v.y + v.z * v.z + v.w * v.w;
#pragma unroll
  for (int off = 32; off > 0; off >>= 1) {
    sm += __shfl_down(sm, off);
    sq += __shfl_down(sq, off);
  }
  __shared__ float red[16];
  const int w = t >> 6, lane = t & 63;
  if (lane == 0) { red[w] = sm; red[8 + w] = sq; }
  __syncthreads();
  if (t == 0) {
    const float ts = red[0] + red[1] + red[2] + red[3];
    const float tq = red[8] + red[9] + red[10] + red[11];
    const float mean = ts * (1.0f / 1024.0f);
    const float var = tq * (1.0f / 1024.0f) - mean * mean;
    red[0] = mean;
    red[1] = rsqrtf(var + 1e-5f);
  }
  __syncthreads();
  const float mean = red[0], rstd = red[1];
  const float4 gg = ((const float4*)g)[t];
  const float4 bb2 = ((const float4*)bta)[t];
  bf16x4 ov;
  ov[0] = (bf16_t)((v.x - mean) * rstd * gg.x + bb2.x);
  ov[1] = (bf16_t)((v.y - mean) * rstd * gg.y + bb2.y);
  ov[2] = (bf16_t)((v.z - mean) * rstd * gg.z + bb2.z);
  ov[3] = (bf16_t)((v.w - mean) * rstd * gg.w + bb2.w);
  ((bf16x4*)(o + ((long)bb * B_ROWS + s) * 1024))[t] = ov;
}

// ---------------- GEMM C = A @ W^T (+epilogue) ----------------
// A [M_P,K] bf16 row-major (batch-padded rows), W [N,K] bf16 row-major.
// 128x128 tile, BK=32, 4 waves 2x2, 4x4 MFMA 16x16x32 each.
// 1-D grid, XCD-swizzled: bid&7 = XCD slice of 17 m-tiles, n fastest within.
enum { EPI_QKV = 0, EPI_PROJ = 1, EPI_FC1 = 2, EPI_FC2 = 3 };

template <int EPI>
__global__ __launch_bounds__(256) void gemm_bt(const bf16_t* __restrict__ A,
                                               const bf16_t* __restrict__ W,
                                               const float* __restrict__ bias,
                                               const float* __restrict__ resid,
                                               const float* __restrict__ ls,
                                               bf16_t* __restrict__ outb,
                                               float* __restrict__ outf,
                                               bf16_t* __restrict__ vt,
                                               int N, int K, int NT) {
  const int g = blockIdx.x & 7;
  const int rr = blockIdx.x >> 3;
  const int ntile = rr % NT;
  const int mloc = rr / NT;
  const int mtile = g * 17 + mloc;
  if (mtile >= 129) return;
  const int n0 = ntile * 128;
  const int m0 = mtile * 128;

  // LDS overlay: K-loop uses first 16KB (A 8K | B 8K); epilogue restages C (<=34304B)
  __shared__ __align__(16) char smem[34304];
  bf16_t* ldsA = (bf16_t*)smem;
  bf16_t* ldsB = (bf16_t*)(smem + 8192);

  const int t = threadIdx.x;
  const int w = t >> 6;
  const int lane = t & 63;
  const int wm = (w >> 1) * 64;
  const int wn = (w & 1) * 64;
  const int ln = lane & 15;
  const int quad = lane >> 4;

  const f32x4 zero4 = {0.0f, 0.0f, 0.0f, 0.0f};
  f32x4 acc[4][4];
#pragma unroll
  for (int i = 0; i < 4; ++i)
#pragma unroll
    for (int j = 0; j < 4; ++j) acc[i][j] = zero4;

  const int r0 = t >> 2, kc0 = (t & 3) * 8;
  const int r1 = (t + 256) >> 2, kc1 = ((t + 256) & 3) * 8;
  const bf16_t* a0 = A + (long)(m0 + r0) * K + kc0;
  const bf16_t* a1 = A + (long)(m0 + r1) * K + kc1;
  const bf16_t* b0 = W + (long)(n0 + r0) * K + kc0;
  const bf16_t* b1 = W + (long)(n0 + r1) * K + kc1;

  for (int kt = 0; kt < K; kt += 32) {
    __syncthreads();
    __builtin_amdgcn_global_load_lds((const __attribute__((address_space(1))) void*)(a0 + kt),
                                     (__attribute__((address_space(3))) void*)&ldsA[t * 8], 16, 0, 0);
    __builtin_amdgcn_global_load_lds((const __attribute__((address_space(1))) void*)(a1 + kt),
                                     (__attribute__((address_space(3))) void*)&ldsA[(t + 256) * 8], 16, 0, 0);
    __builtin_amdgcn_global_load_lds((const __attribute__((address_space(1))) void*)(b0 + kt),
                                     (__attribute__((address_space(3))) void*)&ldsB[t * 8], 16, 0, 0);
    __builtin_amdgcn_global_load_lds((const __attribute__((address_space(1))) void*)(b1 + kt),
                                     (__attribute__((address_space(3))) void*)&ldsB[(t + 256) * 8], 16, 0, 0);
    __syncthreads();

    bf16x8 af[4], bfr[4];
#pragma unroll
    for (int mt = 0; mt < 4; ++mt)
      af[mt] = *(const bf16x8*)&ldsA[(wm + mt * 16 + ln) * 32 + quad * 8];
#pragma unroll
    for (int nt = 0; nt < 4; ++nt)
      bfr[nt] = *(const bf16x8*)&ldsB[(wn + nt * 16 + ln) * 32 + quad * 8];
#pragma unroll
    for (int mt = 0; mt < 4; ++mt)
#pragma unroll
      for (int nt = 0; nt < 4; ++nt)
        acc[mt][nt] = __builtin_amdgcn_mfma_f32_16x16x32_bf16(af[mt], bfr[nt], acc[mt][nt], 0, 0, 0);
  }
  __syncthreads();  // drain last ds_reads before C-stage overwrites LDS

  // C/D frag layout: col = lane&15, row = quad*4+reg (m89-verified)
  if (EPI == EPI_PROJ || EPI == EPI_FC2) {
    // fp32 + residual to unpadded d_out; scalar stores are full-line (64B/quad)
    const int b0r = m0 / B_ROWS;
    const int s0 = m0 - b0r * B_ROWS;
#pragma unroll
    for (int nt = 0; nt < 4; ++nt) {
      const int n = n0 + wn + nt * 16 + ln;
      const float bn = bias[n];
      const float lsn = ls[n];
#pragma unroll
      for (int mt = 0; mt < 4; ++mt) {
#pragma unroll
        for (int r = 0; r < 4; ++r) {
          const int d = wm + mt * 16 + quad * 4 + r;
          int s = s0 + d, b = b0r;
          if (s >= B_ROWS) { s -= B_ROWS; ++b; }
          if (s < S_LEN) {
            const long idx = ((long)b * S_LEN + s) * 1024 + n;
            outf[idx] = resid[idx] + lsn * (acc[mt][nt][r] + bn);
          }
        }
      }
    }
    return;
  }

  if (EPI == EPI_QKV && n0 >= 2048) {
    // V -> transposed C-stage [n_local][m_local], stride 134, then vector store along s
    bf16_t* C = (bf16_t*)smem;
#pragma unroll
    for (int nt = 0; nt < 4; ++nt) {
      const int nl = wn + nt * 16 + ln;
      const float bn = bias[n0 + nl];
#pragma unroll
      for (int mt = 0; mt < 4; ++mt)
#pragma unroll
        for (int r = 0; r < 4; ++r)
          C[nl * 134 + (wm + mt * 16 + quad * 4 + r)] = (bf16_t)(acc[mt][nt][r] + bn);
    }
    __syncthreads();
    const int b0r = m0 / B_ROWS;
    const int s0 = m0 - b0r * B_ROWS;
#pragma unroll
    for (int p = 0; p < 8; ++p) {
      const int nl = p * 16 + (t >> 4);
      const int sc = (t & 15) * 8;
      const int n = n0 + nl;
      const int h = (n >> 6) - 32, d = n & 63;
      int s = s0 + sc, b = b0r;
      if (s >= B_ROWS) { s -= B_ROWS; ++b; }
      *(bf16x8*)&vt[(((long)b * 16 + h) * 64 + d) * (long)SP + s] =
          *(const bf16x8*)&C[nl * 134 + sc];
    }
    return;
  }

  // QKV-qk / FC1: C-stage [m_local][n_local], stride 132, then row-contiguous b128 stores
  {
    bf16_t* C = (bf16_t*)smem;
#pragma unroll
    for (int nt = 0; nt < 4; ++nt) {
      const int nl = wn + nt * 16 + ln;
      const float bn = bias[n0 + nl];
#pragma unroll
      for (int mt = 0; mt < 4; ++mt)
#pragma unroll
        for (int r = 0; r < 4; ++r) {
          float c = acc[mt][nt][r] + bn;
          if (EPI == EPI_FC1) c = c / (1.0f + __expf(-1.702f * c));  // sigmoid-GELU
          C[(wm + mt * 16 + quad * 4 + r) * 132 + nl] = (bf16_t)c;
        }
    }
    __syncthreads();
    const long stride = (EPI == EPI_QKV) ? 2048 : N;
#pragma unroll
    for (int p = 0; p < 8; ++p) {
      const int row = p * 16 + (t >> 4);
      const int sc = (t & 15) * 8;
      *(bf16x8*)&outb[(long)(m0 + row) * stride + n0 + sc] = *(const bf16x8*)&C[row * 132 + sc];
    }
  }
}

// ---------------- Flash attention, 128-key tiles ----------------
__global__ __launch_bounds__(256) void attn_kernel(const bf16_t* __restrict__ qk,
                                                   const bf16_t* __restrict__ vt,
                                                   bf16_t* __restrict__ out) {
  const int bh = blockIdx.y;
  const int b = bh >> 4, h = bh & 15;
  const int q0 = blockIdx.x * 64;
  const int t = threadIdx.x;
  const int wv = t >> 6, lane = t & 63;
  const int ln = lane & 15, quad = lane >> 4;

  __shared__ bf16_t ldsK[128][72];
  __shared__ bf16_t ldsV[64][136];
  __shared__ bf16_t ldsP[4][16][136];

  const long rowbase = (long)b * B_ROWS;

  int qrow = q0 + wv * 16 + ln;
  if (qrow > S_LEN - 1) qrow = S_LEN - 1;
  const bf16_t* qp = qk + (rowbase + qrow) * 2048 + h * 64;
  const bf16x8 qf0 = *(const bf16x8*)(qp + quad * 8);
  const bf16x8 qf1 = *(const bf16x8*)(qp + 32 + quad * 8);

  const bf16_t* vbase = vt + (long)bh * 64 * SP;

  const f32x4 zero4 = {0.0f, 0.0f, 0.0f, 0.0f};
  f32x4 oacc[4];
  float m_run[4], l_run[4];
#pragma unroll
  for (int i = 0; i < 4; ++i) { oacc[i] = zero4; m_run[i] = -1e30f; l_run[i] = 0.0f; }

  for (int k0 = 0; k0 < S_LEN; k0 += 128) {
    __syncthreads();
#pragma unroll
    for (int i = 0; i < 4; ++i) {
      const int slot = t + i * 256;
      const int key = slot >> 3, ch = (slot & 7) * 8;
      int krow = k0 + key;
      if (krow > S_LEN - 1) krow = S_LEN - 1;
      *(bf16x8*)&ldsK[key][ch] =
          *(const bf16x8*)(qk + (rowbase + krow) * 2048 + 1024 + h * 64 + ch);
    }
#pragma unroll
    for (int i = 0; i < 4; ++i) {
      const int slot = t + i * 256;
      const int dim = slot >> 4, kc = (slot & 15) * 8;
      *(bf16x8*)&ldsV[dim][kc] = *(const bf16x8*)(vbase + (long)dim * SP + k0 + kc);
    }
    __syncthreads();

    f32x4 s[8];
#pragma unroll
    for (int nt = 0; nt < 8; ++nt) {
      const bf16x8 kf0 = *(const bf16x8*)&ldsK[nt * 16 + ln][quad * 8];
      const bf16x8 kf1 = *(const bf16x8*)&ldsK[nt * 16 + ln][32 + quad * 8];
      f32x4 a = zero4;
      a = __builtin_amdgcn_mfma_f32_16x16x32_bf16(qf0, kf0, a, 0, 0, 0);
      a = __builtin_amdgcn_mfma_f32_16x16x32_bf16(qf1, kf1, a, 0, 0, 0);
      const bool valid = (k0 + nt * 16 + ln) < S_LEN;
#pragma unroll
      for (int r = 0; r < 4; ++r) s[nt][r] = valid ? a[r] * 0.125f : -1e30f;
    }

    float mx[4];
#pragma unroll
    for (int r = 0; r < 4; ++r) mx[r] = s[0][r];
#pragma unroll
    for (int nt = 1; nt < 8; ++nt)
#pragma unroll
      for (int r = 0; r < 4; ++r) mx[r] = fmaxf(mx[r], s[nt][r]);
#pragma unroll
    for (int off = 1; off < 16; off <<= 1)
#pragma unroll
      for (int r = 0; r < 4; ++r) mx[r] = fmaxf(mx[r], __shfl_xor(mx[r], off));

    float alpha[4];
#pragma unroll
    for (int r = 0; r < 4; ++r) {
      const float mnew = fmaxf(m_run[r], mx[r]);
      alpha[r] = __expf(m_run[r] - mnew);
      m_run[r] = mnew;
    }

    float rs[4] = {0.0f, 0.0f, 0.0f, 0.0f};
#pragma unroll
    for (int nt = 0; nt < 8; ++nt)
#pragma unroll
      for (int r = 0; r < 4; ++r) {
        const float p = __expf(s[nt][r] - m_run[r]);
        rs[r] += p;
        ldsP[wv][quad * 4 + r][nt * 16 + ln] = (bf16_t)p;
      }
#pragma unroll
    for (int off = 1; off < 16; off <<= 1)
#pragma unroll
      for (int r = 0; r < 4; ++r) rs[r] += __shfl_xor(rs[r], off);
#pragma unroll
    for (int r = 0; r < 4; ++r) l_run[r] = l_run[r] * alpha[r] + rs[r];

#pragma unroll
    for (int dt = 0; dt < 4; ++dt)
#pragma unroll
      for (int r = 0; r < 4; ++r) oacc[dt][r] *= alpha[r];

#pragma unroll
    for (int ko = 0; ko < 4; ++ko) {
      const bf16x8 pf = *(const bf16x8*)&ldsP[wv][ln][ko * 32 + quad * 8];
#pragma unroll
      for (int dt = 0; dt < 4; ++dt) {
        const bf16x8 vf = *(const bf16x8*)&ldsV[dt * 16 + ln][ko * 32 + quad * 8];
        oacc[dt] = __builtin_amdgcn_mfma_f32_16x16x32_bf16(pf, vf, oacc[dt], 0, 0, 0);
      }
    }
  }

#pragma unroll
  for (int r = 0; r < 4; ++r) {
    const int q = q0 + wv * 16 + quad * 4 + r;
    if (q < S_LEN) {
      const float inv = 1.0f / l_run[r];
#pragma unroll
      for (int dt = 0; dt < 4; ++dt)
        out[(rowbase + q) * 1024 + h * 64 + dt * 16 + ln] = (bf16_t)(oacc[dt][r] * inv);
    }
  }
}

// ---------------- launch ----------------
extern "C" void kernel_launch(void* const* d_in, const int* in_sizes, int n_in,
                              void* d_out, int out_size, void* d_ws, size_t ws_size,
                              hipStream_t stream) {
  (void)in_sizes; (void)n_in; (void)out_size; (void)ws_size;
  const float* hidden = (const float*)d_in[0];
  const float* n1g = (const float*)d_in[1];
  const float* n1b = (const float*)d_in[2];
  const float* qkv_w = (const float*)d_in[3];
  const float* qkv_b = (const float*)d_in[4];
  const float* proj_w = (const float*)d_in[5];
  const float* proj_b = (const float*)d_in[6];
  const float* ls1 = (const float*)d_in[7];
  const float* n2g = (const float*)d_in[8];
  const float* n2b = (const float*)d_in[9];
  const float* fc1_w = (const float*)d_in[10];
  const float* fc1_b = (const float*)d_in[11];
  const float* fc2_w = (const float*)d_in[12];
  const float* fc2_b = (const float*)d_in[13];
  const float* ls2 = (const float*)d_in[14];
  float* out = (float*)d_out;

  // workspace layout (bytes):
  //  R1:     16512*1024*2 = 33,816,576      (xnorm -> attn_out -> ynorm, padded rows)
  //  SHARED: 135,266,304   {qk 67,633,152 + vt 37,748,736}  OR  gelu 16512*4096*2
  //  W:      bf16 weights 25,165,824 (qkv|proj|fc1|fc2 contiguous)
  char* ws = (char*)d_ws;
  bf16_t* R1 = (bf16_t*)ws;
  char* shared = ws + 33816576L;
  bf16_t* qkbuf = (bf16_t*)shared;                  // [16512, 2048]
  bf16_t* vtbuf = (bf16_t*)(shared + 67633152L);    // [256, 64, SP]
  bf16_t* gelu = (bf16_t*)shared;                   // [16512, 4096]
  bf16_t* wqkv = (bf16_t*)(ws + 33816576L + 135266304L);
  bf16_t* wproj = wqkv + 3145728;
  bf16_t* wfc1 = wproj + 1048576;
  bf16_t* wfc2 = wfc1 + 4194304;

  // all weight converts in one launch (12288 * 256 * 4 floats)
  cvt_kernel<<<12288, 256, 0, stream>>>(qkv_w, proj_w, fc1_w, fc2_w, wqkv);

  // LN1: hidden -> R1 (bf16, padded rows)
  ln_kernel<<<dim3(S_LEN, 16), 256, 0, stream>>>(hidden, n1g, n1b, R1);

  // QKV: Q,K -> qkbuf [M_P,2048]; V -> vtbuf transposed
  gemm_bt<EPI_QKV><<<136 * 24, 256, 0, stream>>>(R1, wqkv, qkv_b, nullptr, nullptr,
                                                 qkbuf, nullptr, vtbuf, 3072, 1024, 24);

  // attention: qkbuf/vtbuf -> R1 [M_P,1024]
  attn_kernel<<<dim3(17, 256), 256, 0, stream>>>(qkbuf, vtbuf, R1);

  // proj + residual: out = hidden + ls1*(R1 @ wproj^T + b)
  gemm_bt<EPI_PROJ><<<136 * 8, 256, 0, stream>>>(R1, wproj, proj_b, hidden, ls1,
                                                 nullptr, out, nullptr, 1024, 1024, 8);

  // LN2: out -> R1
  ln_kernel<<<dim3(S_LEN, 16), 256, 0, stream>>>(out, n2g, n2b, R1);

  // FC1 + GELU: R1 @ wfc1^T + b -> gelu [M_P,4096]
  gemm_bt<EPI_FC1><<<136 * 32, 256, 0, stream>>>(R1, wfc1, fc1_b, nullptr, nullptr,
                                                 gelu, nullptr, nullptr, 4096, 1024, 32);

  // FC2 + residual: out += ls2*(gelu @ wfc2^T + b)
  gemm_bt<EPI_FC2><<<136 * 8, 256, 0, stream>>>(gelu, wfc2, fc2_b, out, ls2,
                                                nullptr, out, nullptr, 1024, 4096, 8);
}

// Round 4
// 1128.513 us; speedup vs baseline: 1.3965x; 1.0995x over previous
//
#include <hip/hip_runtime.h>

typedef __bf16 bf16_t;
typedef bf16_t bf16x8 __attribute__((ext_vector_type(8)));
typedef bf16_t bf16x4 __attribute__((ext_vector_type(4)));
typedef float f32x4 __attribute__((ext_vector_type(4)));

#define S_LEN 1025
#define B_ROWS 1032    // per-batch padded rows (8*129); 16*1032 = 16512 = 129 tiles
#define M_P 16512
#define SP 1152        // padded seq stride for V^T (9*128)

// ---------------- fp32 -> bf16 convert (all 4 weight blobs, one launch) ----------------
__global__ __launch_bounds__(256) void cvt_kernel(const float* __restrict__ qkv_w,
                                                  const float* __restrict__ proj_w,
                                                  const float* __restrict__ fc1_w,
                                                  const float* __restrict__ fc2_w,
                                                  bf16_t* __restrict__ out) {
  const int i = blockIdx.x * 256 + threadIdx.x;  // vec4 index, total 3145728
  const float* src;
  int j = i;
  if (j < 786432) src = qkv_w;
  else if ((j -= 786432) < 262144) src = proj_w;
  else if ((j -= 262144) < 1048576) src = fc1_w;
  else { j -= 1048576; src = fc2_w; }
  const float4 v = ((const float4*)src)[j];
  bf16x4 o;
  o[0] = (bf16_t)v.x; o[1] = (bf16_t)v.y; o[2] = (bf16_t)v.z; o[3] = (bf16_t)v.w;
  ((bf16x4*)out)[i] = o;
}

// ---------------- LayerNorm (fp32 unpadded in -> bf16 padded out) ----------------
__global__ __launch_bounds__(256) void ln_kernel(const float* __restrict__ x,
                                                 const float* __restrict__ g,
                                                 const float* __restrict__ bta,
                                                 bf16_t* __restrict__ o) {
  const int s = blockIdx.x, bb = blockIdx.y;
  const int t = threadIdx.x;
  const float4 v = ((const float4*)(x + ((long)bb * S_LEN + s) * 1024))[t];
  float sm = v.x + v.y + v.z + v.w;
  float sq = v.x * v.x + v.y * v.y + v.z * v.z + v.w * v.w;
#pragma unroll
  for (int off = 32; off > 0; off >>= 1) {
    sm += __shfl_down(sm, off);
    sq += __shfl_down(sq, off);
  }
  __shared__ float red[16];
  const int w = t >> 6, lane = t & 63;
  if (lane == 0) { red[w] = sm; red[8 + w] = sq; }
  __syncthreads();
  if (t == 0) {
    const float ts = red[0] + red[1] + red[2] + red[3];
    const float tq = red[8] + red[9] + red[10] + red[11];
    const float mean = ts * (1.0f / 1024.0f);
    const float var = tq * (1.0f / 1024.0f) - mean * mean;
    red[0] = mean;
    red[1] = rsqrtf(var + 1e-5f);
  }
  __syncthreads();
  const float mean = red[0], rstd = red[1];
  const float4 gg = ((const float4*)g)[t];
  const float4 bb2 = ((const float4*)bta)[t];
  bf16x4 ov;
  ov[0] = (bf16_t)((v.x - mean) * rstd * gg.x + bb2.x);
  ov[1] = (bf16_t)((v.y - mean) * rstd * gg.y + bb2.y);
  ov[2] = (bf16_t)((v.z - mean) * rstd * gg.z + bb2.z);
  ov[3] = (bf16_t)((v.w - mean) * rstd * gg.w + bb2.w);
  ((bf16x4*)(o + ((long)bb * B_ROWS + s) * 1024))[t] = ov;
}

// ---------------- GEMM C = A @ W^T (+epilogue) ----------------
// A [M_P,K] bf16 row-major (batch-padded rows), W [N,K] bf16 row-major.
// 128x128 tile, BK=32, 4 waves 2x2, 4x4 MFMA 16x16x32 each.
// 1-D grid, XCD-swizzled: bid&7 = XCD slice of 17 m-tiles, n fastest within.
enum { EPI_QKV = 0, EPI_PROJ = 1, EPI_FC1 = 2, EPI_FC2 = 3 };

template <int EPI>
__global__ __launch_bounds__(256) void gemm_bt(const bf16_t* __restrict__ A,
                                               const bf16_t* __restrict__ W,
                                               const float* __restrict__ bias,
                                               const float* __restrict__ resid,
                                               const float* __restrict__ ls,
                                               bf16_t* __restrict__ outb,
                                               float* __restrict__ outf,
                                               bf16_t* __restrict__ vt,
                                               int N, int K, int NT) {
  const int g = blockIdx.x & 7;
  const int rr = blockIdx.x >> 3;
  const int ntile = rr % NT;
  const int mloc = rr / NT;
  const int mtile = g * 17 + mloc;
  if (mtile >= 129) return;
  const int n0 = ntile * 128;
  const int m0 = mtile * 128;

  // LDS overlay: K-loop uses first 16KB (A 8K | B 8K); epilogue restages C (<=34304B)
  __shared__ __align__(16) char smem[34304];
  bf16_t* ldsA = (bf16_t*)smem;
  bf16_t* ldsB = (bf16_t*)(smem + 8192);

  const int t = threadIdx.x;
  const int w = t >> 6;
  const int lane = t & 63;
  const int wm = (w >> 1) * 64;
  const int wn = (w & 1) * 64;
  const int ln = lane & 15;
  const int quad = lane >> 4;

  const f32x4 zero4 = {0.0f, 0.0f, 0.0f, 0.0f};
  f32x4 acc[4][4];
#pragma unroll
  for (int i = 0; i < 4; ++i)
#pragma unroll
    for (int j = 0; j < 4; ++j) acc[i][j] = zero4;

  const int r0 = t >> 2, kc0 = (t & 3) * 8;
  const int r1 = (t + 256) >> 2, kc1 = ((t + 256) & 3) * 8;
  const bf16_t* a0 = A + (long)(m0 + r0) * K + kc0;
  const bf16_t* a1 = A + (long)(m0 + r1) * K + kc1;
  const bf16_t* b0 = W + (long)(n0 + r0) * K + kc0;
  const bf16_t* b1 = W + (long)(n0 + r1) * K + kc1;

  for (int kt = 0; kt < K; kt += 32) {
    __syncthreads();
    __builtin_amdgcn_global_load_lds((const __attribute__((address_space(1))) void*)(a0 + kt),
                                     (__attribute__((address_space(3))) void*)&ldsA[t * 8], 16, 0, 0);
    __builtin_amdgcn_global_load_lds((const __attribute__((address_space(1))) void*)(a1 + kt),
                                     (__attribute__((address_space(3))) void*)&ldsA[(t + 256) * 8], 16, 0, 0);
    __builtin_amdgcn_global_load_lds((const __attribute__((address_space(1))) void*)(b0 + kt),
                                     (__attribute__((address_space(3))) void*)&ldsB[t * 8], 16, 0, 0);
    __builtin_amdgcn_global_load_lds((const __attribute__((address_space(1))) void*)(b1 + kt),
                                     (__attribute__((address_space(3))) void*)&ldsB[(t + 256) * 8], 16, 0, 0);
    __syncthreads();

    bf16x8 af[4], bfr[4];
#pragma unroll
    for (int mt = 0; mt < 4; ++mt)
      af[mt] = *(const bf16x8*)&ldsA[(wm + mt * 16 + ln) * 32 + quad * 8];
#pragma unroll
    for (int nt = 0; nt < 4; ++nt)
      bfr[nt] = *(const bf16x8*)&ldsB[(wn + nt * 16 + ln) * 32 + quad * 8];
#pragma unroll
    for (int mt = 0; mt < 4; ++mt)
#pragma unroll
      for (int nt = 0; nt < 4; ++nt)
        acc[mt][nt] = __builtin_amdgcn_mfma_f32_16x16x32_bf16(af[mt], bfr[nt], acc[mt][nt], 0, 0, 0);
  }
  __syncthreads();  // drain last ds_reads before C-stage overwrites LDS

  // C/D frag layout: col = lane&15, row = quad*4+reg (m89-verified)
  if (EPI == EPI_PROJ || EPI == EPI_FC2) {
    const int b0r = m0 / B_ROWS;
    const int s0 = m0 - b0r * B_ROWS;
#pragma unroll
    for (int nt = 0; nt < 4; ++nt) {
      const int n = n0 + wn + nt * 16 + ln;
      const float bn = bias[n];
      const float lsn = ls[n];
#pragma unroll
      for (int mt = 0; mt < 4; ++mt) {
#pragma unroll
        for (int r = 0; r < 4; ++r) {
          const int d = wm + mt * 16 + quad * 4 + r;
          int s = s0 + d, b = b0r;
          if (s >= B_ROWS) { s -= B_ROWS; ++b; }
          if (s < S_LEN) {
            const long idx = ((long)b * S_LEN + s) * 1024 + n;
            outf[idx] = resid[idx] + lsn * (acc[mt][nt][r] + bn);
          }
        }
      }
    }
    return;
  }

  if (EPI == EPI_QKV && n0 >= 2048) {
    // V -> transposed C-stage [n_local][m_local], stride 134, then vector store along s
    bf16_t* C = (bf16_t*)smem;
#pragma unroll
    for (int nt = 0; nt < 4; ++nt) {
      const int nl = wn + nt * 16 + ln;
      const float bn = bias[n0 + nl];
#pragma unroll
      for (int mt = 0; mt < 4; ++mt)
#pragma unroll
        for (int r = 0; r < 4; ++r)
          C[nl * 134 + (wm + mt * 16 + quad * 4 + r)] = (bf16_t)(acc[mt][nt][r] + bn);
    }
    __syncthreads();
    const int b0r = m0 / B_ROWS;
    const int s0 = m0 - b0r * B_ROWS;
#pragma unroll
    for (int p = 0; p < 8; ++p) {
      const int nl = p * 16 + (t >> 4);
      const int sc = (t & 15) * 8;
      const int n = n0 + nl;
      const int h = (n >> 6) - 32, d = n & 63;
      int s = s0 + sc, b = b0r;
      if (s >= B_ROWS) { s -= B_ROWS; ++b; }
      *(bf16x8*)&vt[(((long)b * 16 + h) * 64 + d) * (long)SP + s] =
          *(const bf16x8*)&C[nl * 134 + sc];
    }
    return;
  }

  // QKV-qk / FC1: C-stage [m_local][n_local], stride 132, then row-contiguous b128 stores
  {
    bf16_t* C = (bf16_t*)smem;
#pragma unroll
    for (int nt = 0; nt < 4; ++nt) {
      const int nl = wn + nt * 16 + ln;
      const float bn = bias[n0 + nl];
#pragma unroll
      for (int mt = 0; mt < 4; ++mt)
#pragma unroll
        for (int r = 0; r < 4; ++r) {
          float c = acc[mt][nt][r] + bn;
          if (EPI == EPI_FC1) c = c / (1.0f + __expf(-1.702f * c));  // sigmoid-GELU
          C[(wm + mt * 16 + quad * 4 + r) * 132 + nl] = (bf16_t)c;
        }
    }
    __syncthreads();
    const long stride = (EPI == EPI_QKV) ? 2048 : N;
#pragma unroll
    for (int p = 0; p < 8; ++p) {
      const int row = p * 16 + (t >> 4);
      const int sc = (t & 15) * 8;
      *(bf16x8*)&outb[(long)(m0 + row) * stride + n0 + sc] = *(const bf16x8*)&C[row * 132 + sc];
    }
  }
}

// ---------------- Flash attention, 128-key tiles, no-max exp2 softmax ----------------
// 1-D grid 4352 = 8 XCD-groups x (32 bh x 17 qtiles); all qtiles of a bh share an XCD.
// LDS: ldsK[128][72] (18432B, overlaid by ldsP[4][16][136] after scores) + ldsV[64][136]
// = 35840B -> 4 blocks/CU.
#define SCL 0.18033688f   // 0.125 * log2(e)

__global__ __launch_bounds__(256) void attn_kernel(const bf16_t* __restrict__ qk,
                                                   const bf16_t* __restrict__ vt,
                                                   bf16_t* __restrict__ out) {
  const int g = blockIdx.x & 7;
  const int idx = blockIdx.x >> 3;        // 0..543
  const int bh = g * 32 + idx / 17;
  const int q0 = (idx % 17) * 64;
  const int b = bh >> 4, h = bh & 15;
  const int t = threadIdx.x;
  const int wv = t >> 6, lane = t & 63;
  const int ln = lane & 15, quad = lane >> 4;

  __shared__ __align__(16) char smem[35840];
  bf16_t* ldsK = (bf16_t*)smem;             // [128][72]
  bf16_t* ldsP = (bf16_t*)smem;             // [4][16][136] overlay
  bf16_t* ldsV = (bf16_t*)(smem + 18432);   // [64][136]

  const long rowbase = (long)b * B_ROWS;

  int qrow = q0 + wv * 16 + ln;
  if (qrow > S_LEN - 1) qrow = S_LEN - 1;
  const bf16_t* qp = qk + (rowbase + qrow) * 2048 + h * 64;
  const bf16x8 qf0 = *(const bf16x8*)(qp + quad * 8);
  const bf16x8 qf1 = *(const bf16x8*)(qp + 32 + quad * 8);

  const bf16_t* vbase = vt + (long)bh * 64 * SP;

  const f32x4 zero4 = {0.0f, 0.0f, 0.0f, 0.0f};
  f32x4 oacc[4];
  float l_part[4] = {0.0f, 0.0f, 0.0f, 0.0f};
#pragma unroll
  for (int i = 0; i < 4; ++i) oacc[i] = zero4;

  for (int k0 = 0; k0 < 1152; k0 += 128) {
    __syncthreads();
#pragma unroll
    for (int i = 0; i < 4; ++i) {
      const int slot = t + i * 256;
      const int key = slot >> 3, ch = (slot & 7) * 8;
      int krow = k0 + key;
      if (krow > S_LEN - 1) krow = S_LEN - 1;
      *(bf16x8*)&ldsK[key * 72 + ch] =
          *(const bf16x8*)(qk + (rowbase + krow) * 2048 + 1024 + h * 64 + ch);
    }
#pragma unroll
    for (int i = 0; i < 4; ++i) {
      const int slot = t + i * 256;
      const int dim = slot >> 4, kc = (slot & 15) * 8;
      *(bf16x8*)&ldsV[dim * 136 + kc] = *(const bf16x8*)(vbase + (long)dim * SP + k0 + kc);
    }
    __syncthreads();

    // scores (pre-scaled for exp2)
    f32x4 s[8];
#pragma unroll
    for (int nt = 0; nt < 8; ++nt) {
      const bf16x8 kf0 = *(const bf16x8*)&ldsK[(nt * 16 + ln) * 72 + quad * 8];
      const bf16x8 kf1 = *(const bf16x8*)&ldsK[(nt * 16 + ln) * 72 + 32 + quad * 8];
      f32x4 a = zero4;
      a = __builtin_amdgcn_mfma_f32_16x16x32_bf16(qf0, kf0, a, 0, 0, 0);
      a = __builtin_amdgcn_mfma_f32_16x16x32_bf16(qf1, kf1, a, 0, 0, 0);
#pragma unroll
      for (int r = 0; r < 4; ++r) s[nt][r] = a[r] * SCL;
    }
    if (k0 + 128 > S_LEN) {  // tail tile only: mask invalid keys -> p = exp2(-1e30) = 0
#pragma unroll
      for (int nt = 0; nt < 8; ++nt) {
        const bool valid = (k0 + nt * 16 + ln) < S_LEN;
#pragma unroll
        for (int r = 0; r < 4; ++r) s[nt][r] = valid ? s[nt][r] : -1e30f;
      }
    }
    __syncthreads();  // all waves done reading K frags; ldsP may overwrite ldsK

    // p = exp2(s), per-lane partial row-sums (reduced once at the end)
    bf16_t* P = ldsP + wv * 2176;
#pragma unroll
    for (int nt = 0; nt < 8; ++nt)
#pragma unroll
      for (int r = 0; r < 4; ++r) {
        const float p = exp2f(s[nt][r]);
        l_part[r] += p;
        P[(quad * 4 + r) * 136 + nt * 16 + ln] = (bf16_t)p;
      }

    // PV: A = P[q][key] (own wave's region, no barrier needed), B = V^T rows
#pragma unroll
    for (int ko = 0; ko < 4; ++ko) {
      const bf16x8 pf = *(const bf16x8*)&P[ln * 136 + ko * 32 + quad * 8];
#pragma unroll
      for (int dt = 0; dt < 4; ++dt) {
        const bf16x8 vf = *(const bf16x8*)&ldsV[(dt * 16 + ln) * 136 + ko * 32 + quad * 8];
        oacc[dt] = __builtin_amdgcn_mfma_f32_16x16x32_bf16(pf, vf, oacc[dt], 0, 0, 0);
      }
    }
  }

  // l reduction across the 16 lanes of each quad-row group
#pragma unroll
  for (int off = 1; off < 16; off <<= 1)
#pragma unroll
    for (int r = 0; r < 4; ++r) l_part[r] += __shfl_xor(l_part[r], off);

#pragma unroll
  for (int r = 0; r < 4; ++r) {
    const int q = q0 + wv * 16 + quad * 4 + r;
    if (q < S_LEN) {
      const float inv = 1.0f / l_part[r];
#pragma unroll
      for (int dt = 0; dt < 4; ++dt)
        out[(rowbase + q) * 1024 + h * 64 + dt * 16 + ln] = (bf16_t)(oacc[dt][r] * inv);
    }
  }
}

// ---------------- launch ----------------
extern "C" void kernel_launch(void* const* d_in, const int* in_sizes, int n_in,
                              void* d_out, int out_size, void* d_ws, size_t ws_size,
                              hipStream_t stream) {
  (void)in_sizes; (void)n_in; (void)out_size; (void)ws_size;
  const float* hidden = (const float*)d_in[0];
  const float* n1g = (const float*)d_in[1];
  const float* n1b = (const float*)d_in[2];
  const float* qkv_w = (const float*)d_in[3];
  const float* qkv_b = (const float*)d_in[4];
  const float* proj_w = (const float*)d_in[5];
  const float* proj_b = (const float*)d_in[6];
  const float* ls1 = (const float*)d_in[7];
  const float* n2g = (const float*)d_in[8];
  const float* n2b = (const float*)d_in[9];
  const float* fc1_w = (const float*)d_in[10];
  const float* fc1_b = (const float*)d_in[11];
  const float* fc2_w = (const float*)d_in[12];
  const float* fc2_b = (const float*)d_in[13];
  const float* ls2 = (const float*)d_in[14];
  float* out = (float*)d_out;

  // workspace layout (bytes):
  //  R1:     16512*1024*2 = 33,816,576      (xnorm -> attn_out -> ynorm, padded rows)
  //  SHARED: 135,266,304   {qk 67,633,152 + vt 37,748,736}  OR  gelu 16512*4096*2
  //  W:      bf16 weights 25,165,824 (qkv|proj|fc1|fc2 contiguous)
  char* ws = (char*)d_ws;
  bf16_t* R1 = (bf16_t*)ws;
  char* shared = ws + 33816576L;
  bf16_t* qkbuf = (bf16_t*)shared;                  // [16512, 2048]
  bf16_t* vtbuf = (bf16_t*)(shared + 67633152L);    // [256, 64, SP]
  bf16_t* gelu = (bf16_t*)shared;                   // [16512, 4096]
  bf16_t* wqkv = (bf16_t*)(ws + 33816576L + 135266304L);
  bf16_t* wproj = wqkv + 3145728;
  bf16_t* wfc1 = wproj + 1048576;
  bf16_t* wfc2 = wfc1 + 4194304;

  cvt_kernel<<<12288, 256, 0, stream>>>(qkv_w, proj_w, fc1_w, fc2_w, wqkv);

  // LN1: hidden -> R1 (bf16, padded rows)
  ln_kernel<<<dim3(S_LEN, 16), 256, 0, stream>>>(hidden, n1g, n1b, R1);

  // QKV: Q,K -> qkbuf [M_P,2048]; V -> vtbuf transposed
  gemm_bt<EPI_QKV><<<136 * 24, 256, 0, stream>>>(R1, wqkv, qkv_b, nullptr, nullptr,
                                                 qkbuf, nullptr, vtbuf, 3072, 1024, 24);

  // attention: qkbuf/vtbuf -> R1 [M_P,1024]
  attn_kernel<<<4352, 256, 0, stream>>>(qkbuf, vtbuf, R1);

  // proj + residual: out = hidden + ls1*(R1 @ wproj^T + b)
  gemm_bt<EPI_PROJ><<<136 * 8, 256, 0, stream>>>(R1, wproj, proj_b, hidden, ls1,
                                                 nullptr, out, nullptr, 1024, 1024, 8);

  // LN2: out -> R1
  ln_kernel<<<dim3(S_LEN, 16), 256, 0, stream>>>(out, n2g, n2b, R1);

  // FC1 + GELU: R1 @ wfc1^T + b -> gelu [M_P,4096]
  gemm_bt<EPI_FC1><<<136 * 32, 256, 0, stream>>>(R1, wfc1, fc1_b, nullptr, nullptr,
                                                 gelu, nullptr, nullptr, 4096, 1024, 32);

  // FC2 + residual: out += ls2*(gelu @ wfc2^T + b)
  gemm_bt<EPI_FC2><<<136 * 8, 256, 0, stream>>>(gelu, wfc2, fc2_b, out, ls2,
                                                nullptr, out, nullptr, 1024, 4096, 8);
}